// Round 9
// baseline (651629.199 us; speedup 1.0000x reference)
//
#include <hip/hip_runtime.h>

#define HID 2048
#define IN_DIM 512
#define TSTEPS 1024
#define NBLK 256
#define NTHR 320   // 256 compute threads + dedicated poller wave (clock runs ahead)
#define NCMP 256
#define KS 66      // chunk stride (floats): 2-way bank alias = free, 8B aligned

typedef unsigned long long ull;
typedef unsigned int u32;

__device__ __forceinline__ float reduce32(float v) {
    v += __shfl_xor(v, 16, 64);
    v += __shfl_xor(v, 8, 64);
    v += __shfl_xor(v, 4, 64);
    v += __shfl_xor(v, 2, 64);
    v += __shfl_xor(v, 1, 64);
    return v;
}

__global__ void __launch_bounds__(NTHR, 1)
ode_rnn_main(const float* __restrict__ x, const float* __restrict__ t,
             const float* __restrict__ W_in, const float* __restrict__ b_in,
             const float* __restrict__ W_hid, const float* __restrict__ b_hid,
             const float* __restrict__ W_ode, const float* __restrict__ b_ode,
             const float* __restrict__ W_dec, const float* __restrict__ b_dec,
             const int* __restrict__ nstep_p,
             ull* __restrict__ kb,          // kb[2][HID] tagged (round<<32|bits)
             float* __restrict__ out)
{
    __shared__ float k_lds[2][32 * KS];
    __shared__ u32 cnt[32];        // monotone per-chunk arrival counters
    __shared__ float gv[8];        // per-block row-leader gather
    __shared__ u32 gcnt;           // monotone emission arrivals
    __shared__ u32 clk;            // monotone clock (written by poller wave)

    const int tid = threadIdx.x;
    const int bid = blockIdx.x;
    const int g   = tid & 31;      // lane in 32-group == column-chunk index
    const int grp = tid >> 5;      // 0..7 (compute)
    const int nstep = *nstep_p;
    const int clkline = (bid + 1) & (NBLK - 1);

    if (tid < 32) cnt[tid] = 0;
    if (tid == 0) { gcnt = 0; clk = 0; }
    __syncthreads();               // init visible to all 5 waves; ONLY barrier

    // ========== dedicated poller wave (tid 256..319): clock runs ahead ======
    if (tid >= NCMP) {
        const u32 pmax = 1u + (u32)(TSTEPS - 1) * (4u * (u32)nstep + 1u);
        // uniform poll: whole wave reads the neighbor line's TAIL word
        ull* w0 = kb + (size_t)clkline * 8 + 7;          // parity 0
        ull* w1 = kb + HID + (size_t)clkline * 8 + 7;    // parity 1
        for (u32 q = 1; q <= pmax; ++q) {
            ull* w = (q & 1u) ? w1 : w0;
            while ((u32)(__hip_atomic_load(w, __ATOMIC_RELAXED,
                                           __HIP_MEMORY_SCOPE_AGENT) >> 32) != q) { }
            if (tid == NCMP)
                __hip_atomic_store(&clk, q, __ATOMIC_RELEASE,
                                   __HIP_MEMORY_SCOPE_WORKGROUP);
        }
        return;
    }

    // ======================= compute threads (tid < 256) ====================
    const int row = bid * 8 + grp;

    // ---- per-lane weights ----
    float wode[64];
    {
        const float* wr = W_ode + (size_t)row * HID + g * 64;
#pragma unroll
        for (int q = 0; q < 16; ++q) {
            float4 v = *(const float4*)(wr + 4 * q);
            wode[4*q+0] = v.x; wode[4*q+1] = v.y;
            wode[4*q+2] = v.z; wode[4*q+3] = v.w;
        }
    }
    float win[16];
    {
        const float* wr = W_in + (size_t)row * IN_DIM + g * 16;
#pragma unroll
        for (int q = 0; q < 4; ++q) {
            float4 v = *(const float4*)(wr + 4 * q);
            win[4*q+0] = v.x; win[4*q+1] = v.y;
            win[4*q+2] = v.z; win[4*q+3] = v.w;
        }
    }
    const float breg = b_ode[row];
    const float bsum = b_in[row] + b_hid[row];

    float h[64];

    // ---- emission: row-leaders gather in LDS; 8th arrival stores the line
    //      ascending (word 7 = poller's gate word lands last) ----
    auto emit = [&](u32 p1, float y) {
        if (g == 0) {
            gv[grp] = y;
            u32 old = __hip_atomic_fetch_add(&gcnt, 1u, __ATOMIC_ACQ_REL,
                                             __HIP_MEMORY_SCOPE_WORKGROUP);
            if (old == 8u * p1 - 1u) {         // last of this emission
                ull* dst = kb + (size_t)(p1 & 1u) * HID + (size_t)bid * 8;
#pragma unroll
                for (int e = 0; e < 8; ++e) {
                    ull pv = ((ull)p1 << 32) | (ull)__float_as_uint(gv[e]);
                    __hip_atomic_store(&dst[e], pv, __ATOMIC_RELAXED,
                                       __HIP_MEMORY_SCOPE_AGENT);
                }
            }
        }
    };

    // ---- wait: LDS clk (poller runs ahead -> usually already set) ->
    //      one sweep (tag-verified) -> per-chunk arrival gate ----
    auto wait_all = [&](u32 p) {
        while (__hip_atomic_load(&clk, __ATOMIC_ACQUIRE,
                                 __HIP_MEMORY_SCOPE_WORKGROUP) < p) { }

        ull* src = kb + (size_t)(p & 1u) * HID + (size_t)tid * 8;
        ull w[8];
        for (;;) {
#pragma unroll
            for (int e = 0; e < 8; ++e)
                w[e] = __hip_atomic_load(&src[e], __ATOMIC_RELAXED,
                                         __HIP_MEMORY_SCOPE_AGENT);
            bool ok = true;
#pragma unroll
            for (int e = 0; e < 8; ++e) ok &= ((u32)(w[e] >> 32) == p);
            if (ok) break;
            __builtin_amdgcn_s_sleep(1);      // straggler window only
        }
        float* dst = &k_lds[p & 1u][(tid >> 3) * KS + (tid & 7) * 8];
#pragma unroll
        for (int e = 0; e < 8; ++e) dst[e] = __uint_as_float((u32)w[e]);
        __hip_atomic_fetch_add(&cnt[tid >> 3], 1u, __ATOMIC_RELEASE,
                               __HIP_MEMORY_SCOPE_WORKGROUP);
        const u32 need = 8u * p;
        while (__hip_atomic_load(&cnt[g], __ATOMIC_ACQUIRE,
                                 __HIP_MEMORY_SCOPE_WORKGROUP) < need) { }
    };

    auto dot_chunk = [&](u32 p) -> float {
        const float* base = &k_lds[p & 1u][g * KS];
        float a0 = 0.f, a1 = 0.f, a2 = 0.f, a3 = 0.f;
#pragma unroll
        for (int m = 0; m < 16; ++m) {
            float2 q0 = *(const float2*)(base + 4 * m);
            float2 q1 = *(const float2*)(base + 4 * m + 2);
            a0 = fmaf(wode[4*m+0], q0.x, a0);
            a1 = fmaf(wode[4*m+1], q0.y, a1);
            a2 = fmaf(wode[4*m+2], q1.x, a2);
            a3 = fmaf(wode[4*m+3], q1.y, a3);
        }
        return reduce32((a0 + a1) + (a2 + a3));
    };
    auto h_axpy = [&](u32 p, float coef) {     // off critical path (after emit)
        const float* base = &k_lds[p & 1u][g * KS];
#pragma unroll
        for (int m = 0; m < 32; ++m) {
            float2 q = *(const float2*)(base + 2 * m);
            h[2*m+0] = fmaf(coef, q.x, h[2*m+0]);
            h[2*m+1] = fmaf(coef, q.y, h[2*m+1]);
        }
    };
    auto h_set = [&](u32 p) {
        const float* base = &k_lds[p & 1u][g * KS];
#pragma unroll
        for (int m = 0; m < 32; ++m) {
            float2 q = *(const float2*)(base + 2 * m);
            h[2*m+0] = q.x; h[2*m+1] = q.y;
        }
    };

    // ---- round 1: h0 = tanh(W_in x0 + b_in + b_hid) ----
    {
        const float* xr = x + g * 16;
        float a = 0.f;
#pragma unroll
        for (int q = 0; q < 4; ++q) {
            float4 v = *(const float4*)(xr + 4 * q);
            a = fmaf(win[4*q+0], v.x, a);
            a = fmaf(win[4*q+1], v.y, a);
            a = fmaf(win[4*q+2], v.z, a);
            a = fmaf(win[4*q+3], v.w, a);
        }
        emit(1, tanhf(reduce32(a) + bsum));
    }
    wait_all(1);
    float u_ = dot_chunk(1);
    float ub = u_ + breg;
    emit(2, tanhf(ub));            // k1 of (i=1, s=0)
    h_set(1);
    u32 p = 2;

    for (int i = 1; i < TSTEPS; ++i) {
        const float dt  = (t[i] - t[i - 1]) / (float)nstep;
        const float dt2 = 0.5f * dt;
        const float dt3 = dt * (1.0f / 3.0f);
        const float dt6 = dt * (1.0f / 6.0f);

        for (int s = 0; s < nstep; ++s) {
            const bool last = (s == nstep - 1);
            float w1, w2, w3;
            wait_all(p); w1 = dot_chunk(p);
            emit(p + 1, tanhf(ub + dt2 * w1)); h_axpy(p, dt6); ++p;
            wait_all(p); w2 = dot_chunk(p);
            emit(p + 1, tanhf(ub + dt2 * w2)); h_axpy(p, dt3); ++p;
            wait_all(p); w3 = dot_chunk(p);
            emit(p + 1, tanhf(ub + dt  * w3)); h_axpy(p, dt3); ++p;
            if (!last) {
                wait_all(p); float w4 = dot_chunk(p);
                u_ += dt6 * (w1 + 2.f * (w2 + w3) + w4);
                ub  = u_ + breg;
                emit(p + 1, tanhf(ub)); h_axpy(p, dt6); ++p;
            } else {
                // prefetch W_hid row + x_i while waiting
                const float* wr = W_hid + (size_t)row * HID + g * 64;
                float4 whv[16];
#pragma unroll
                for (int q = 0; q < 16; ++q) whv[q] = *(const float4*)(wr + 4 * q);
                const float* xr = x + (size_t)i * IN_DIM + g * 16;
                float4 xv[4];
#pragma unroll
                for (int q = 0; q < 4; ++q) xv[q] = *(const float4*)(xr + 4 * q);

                wait_all(p);
                h_axpy(p, dt6);               // fold k4 (needed before W_hid.h)
                float a0 = 0.f, a1 = 0.f, a2 = 0.f, a3 = 0.f;
#pragma unroll
                for (int q = 0; q < 16; ++q) {
                    a0 = fmaf(whv[q].x, h[4*q+0], a0);
                    a1 = fmaf(whv[q].y, h[4*q+1], a1);
                    a2 = fmaf(whv[q].z, h[4*q+2], a2);
                    a3 = fmaf(whv[q].w, h[4*q+3], a3);
                }
#pragma unroll
                for (int q = 0; q < 4; ++q) {
                    a0 = fmaf(win[4*q+0], xv[q].x, a0);
                    a1 = fmaf(win[4*q+1], xv[q].y, a1);
                    a2 = fmaf(win[4*q+2], xv[q].z, a2);
                    a3 = fmaf(win[4*q+3], xv[q].w, a3);
                }
                float r = reduce32((a0 + a1) + (a2 + a3));
                emit(p + 1, tanhf(r + bsum)); ++p;   // h_next broadcast
            }
        }
        if (i < TSTEPS - 1) {
            wait_all(p); u_ = dot_chunk(p); ub = u_ + breg;
            emit(p + 1, tanhf(ub)); h_set(p); ++p;   // k1 of next timestep
        } else {
            // final h broadcast at round p: only decode blocks consume
            if (bid < 64) {
                wait_all(p);
                const int r2 = bid * 8 + grp;
                const float* wd = W_dec + (size_t)r2 * HID + g * 64;
                const float* base = &k_lds[p & 1u][g * KS];
                float a0 = 0.f, a1 = 0.f, a2 = 0.f, a3 = 0.f;
#pragma unroll
                for (int m = 0; m < 16; ++m) {
                    float2 q0 = *(const float2*)(base + 4 * m);
                    float2 q1 = *(const float2*)(base + 4 * m + 2);
                    a0 = fmaf(wd[4*m+0], q0.x, a0);
                    a1 = fmaf(wd[4*m+1], q0.y, a1);
                    a2 = fmaf(wd[4*m+2], q1.x, a2);
                    a3 = fmaf(wd[4*m+3], q1.y, a3);
                }
                float r = reduce32((a0 + a1) + (a2 + a3));
                if (g == 0) out[r2] = r + b_dec[r2];
            }
            ++p;
        }
    }
}

extern "C" void kernel_launch(void* const* d_in, const int* in_sizes, int n_in,
                              void* d_out, int out_size, void* d_ws, size_t ws_size,
                              hipStream_t stream) {
    const float* x     = (const float*)d_in[0];
    const float* t     = (const float*)d_in[1];
    const float* W_in  = (const float*)d_in[2];
    const float* b_in  = (const float*)d_in[3];
    const float* W_hid = (const float*)d_in[4];
    const float* b_hid = (const float*)d_in[5];
    const float* W_ode = (const float*)d_in[6];
    const float* b_ode = (const float*)d_in[7];
    const float* W_dec = (const float*)d_in[8];
    const float* b_dec = (const float*)d_in[9];
    const int*   nstep = (const int*)d_in[10];
    ull* kb = (ull*)d_ws;                  // 2*2048*8B = 32 KB; 0xAA poison != any tag
    float* out = (float*)d_out;

    ode_rnn_main<<<dim3(NBLK), dim3(NTHR), 0, stream>>>(
        x, t, W_in, b_in, W_hid, b_hid, W_ode, b_ode, W_dec, b_dec,
        nstep, kb, out);
}

// Round 10
// 642701.318 us; speedup vs baseline: 1.0139x; 1.0139x over previous
//
#include <hip/hip_runtime.h>

#define HID 2048
#define IN_DIM 512
#define TSTEPS 1024
#define NBLK 256
#define NTHR 320   // 256 compute threads + dedicated poller wave (clock runs ahead)
#define NCMP 256
#define KS 66      // chunk stride (floats): 2-way bank alias = free, 8B aligned

typedef unsigned long long ull;
typedef unsigned int u32;

__device__ __forceinline__ float reduce32(float v) {
    v += __shfl_xor(v, 16, 64);
    v += __shfl_xor(v, 8, 64);
    v += __shfl_xor(v, 4, 64);
    v += __shfl_xor(v, 2, 64);
    v += __shfl_xor(v, 1, 64);
    return v;
}

// waves_per_eu capped at 2 -> 256-VGPR budget: compute waves must NOT spill
// (wode[64]+h[64]+win[16] ~ 144+ live floats; r9's 128-VGPR spill cost 2x).
__global__ void __attribute__((amdgpu_flat_work_group_size(NTHR, NTHR),
                               amdgpu_waves_per_eu(1, 2)))
ode_rnn_main(const float* __restrict__ x, const float* __restrict__ t,
             const float* __restrict__ W_in, const float* __restrict__ b_in,
             const float* __restrict__ W_hid, const float* __restrict__ b_hid,
             const float* __restrict__ W_ode, const float* __restrict__ b_ode,
             const float* __restrict__ W_dec, const float* __restrict__ b_dec,
             const int* __restrict__ nstep_p,
             ull* __restrict__ kb,          // kb[2][HID] tagged (round<<32|bits)
             float* __restrict__ out)
{
    __shared__ float k_lds[2][32 * KS];
    __shared__ u32 cnt[32];        // monotone per-chunk arrival counters
    __shared__ float gv[8];        // per-block row-leader gather
    __shared__ u32 gcnt;           // monotone emission arrivals
    __shared__ u32 clk;            // monotone clock (written by poller wave)

    const int tid = threadIdx.x;
    const int bid = blockIdx.x;
    const int g   = tid & 31;      // lane in 32-group == column-chunk index
    const int grp = tid >> 5;      // 0..7 (compute)
    const int nstep = *nstep_p;
    const int clkline = (bid + 1) & (NBLK - 1);

    if (tid < 32) cnt[tid] = 0;
    if (tid == 0) { gcnt = 0; clk = 0; }
    __syncthreads();               // init visible to all 5 waves; ONLY barrier

    // ========== dedicated poller wave (tid 256..319): clock runs ahead ======
    if (tid >= NCMP) {
        const u32 pmax = 1u + (u32)(TSTEPS - 1) * (4u * (u32)nstep + 1u);
        // uniform poll: whole wave reads the neighbor line's TAIL word
        ull* w0 = kb + (size_t)clkline * 8 + 7;          // parity 0
        ull* w1 = kb + HID + (size_t)clkline * 8 + 7;    // parity 1
        for (u32 q = 1; q <= pmax; ++q) {
            ull* w = (q & 1u) ? w1 : w0;
            while ((u32)(__hip_atomic_load(w, __ATOMIC_RELAXED,
                                           __HIP_MEMORY_SCOPE_AGENT) >> 32) != q) { }
            if (tid == NCMP)
                __hip_atomic_store(&clk, q, __ATOMIC_RELEASE,
                                   __HIP_MEMORY_SCOPE_WORKGROUP);
        }
        return;
    }

    // ======================= compute threads (tid < 256) ====================
    const int row = bid * 8 + grp;

    // ---- per-lane weights ----
    float wode[64];
    {
        const float* wr = W_ode + (size_t)row * HID + g * 64;
#pragma unroll
        for (int q = 0; q < 16; ++q) {
            float4 v = *(const float4*)(wr + 4 * q);
            wode[4*q+0] = v.x; wode[4*q+1] = v.y;
            wode[4*q+2] = v.z; wode[4*q+3] = v.w;
        }
    }
    float win[16];
    {
        const float* wr = W_in + (size_t)row * IN_DIM + g * 16;
#pragma unroll
        for (int q = 0; q < 4; ++q) {
            float4 v = *(const float4*)(wr + 4 * q);
            win[4*q+0] = v.x; win[4*q+1] = v.y;
            win[4*q+2] = v.z; win[4*q+3] = v.w;
        }
    }
    const float breg = b_ode[row];
    const float bsum = b_in[row] + b_hid[row];

    float h[64];

    // ---- emission: row-leaders gather in LDS; 8th arrival stores the line
    //      ascending (word 7 = poller's gate word lands last) ----
    auto emit = [&](u32 p1, float y) {
        if (g == 0) {
            gv[grp] = y;
            u32 old = __hip_atomic_fetch_add(&gcnt, 1u, __ATOMIC_ACQ_REL,
                                             __HIP_MEMORY_SCOPE_WORKGROUP);
            if (old == 8u * p1 - 1u) {         // last of this emission
                ull* dst = kb + (size_t)(p1 & 1u) * HID + (size_t)bid * 8;
#pragma unroll
                for (int e = 0; e < 8; ++e) {
                    ull pv = ((ull)p1 << 32) | (ull)__float_as_uint(gv[e]);
                    __hip_atomic_store(&dst[e], pv, __ATOMIC_RELAXED,
                                       __HIP_MEMORY_SCOPE_AGENT);
                }
            }
        }
    };

    // ---- wait: LDS clk (poller runs ahead -> usually already set) ->
    //      one sweep (tag-verified) -> per-chunk arrival gate ----
    auto wait_all = [&](u32 p) {
        while (__hip_atomic_load(&clk, __ATOMIC_ACQUIRE,
                                 __HIP_MEMORY_SCOPE_WORKGROUP) < p) { }

        ull* src = kb + (size_t)(p & 1u) * HID + (size_t)tid * 8;
        ull w[8];
        for (;;) {
#pragma unroll
            for (int e = 0; e < 8; ++e)
                w[e] = __hip_atomic_load(&src[e], __ATOMIC_RELAXED,
                                         __HIP_MEMORY_SCOPE_AGENT);
            bool ok = true;
#pragma unroll
            for (int e = 0; e < 8; ++e) ok &= ((u32)(w[e] >> 32) == p);
            if (ok) break;
            __builtin_amdgcn_s_sleep(1);      // straggler window only
        }
        float* dst = &k_lds[p & 1u][(tid >> 3) * KS + (tid & 7) * 8];
#pragma unroll
        for (int e = 0; e < 8; ++e) dst[e] = __uint_as_float((u32)w[e]);
        __hip_atomic_fetch_add(&cnt[tid >> 3], 1u, __ATOMIC_RELEASE,
                               __HIP_MEMORY_SCOPE_WORKGROUP);
        const u32 need = 8u * p;
        while (__hip_atomic_load(&cnt[g], __ATOMIC_ACQUIRE,
                                 __HIP_MEMORY_SCOPE_WORKGROUP) < need) { }
    };

    auto dot_chunk = [&](u32 p) -> float {
        const float* base = &k_lds[p & 1u][g * KS];
        float a0 = 0.f, a1 = 0.f, a2 = 0.f, a3 = 0.f;
#pragma unroll
        for (int m = 0; m < 16; ++m) {
            float2 q0 = *(const float2*)(base + 4 * m);
            float2 q1 = *(const float2*)(base + 4 * m + 2);
            a0 = fmaf(wode[4*m+0], q0.x, a0);
            a1 = fmaf(wode[4*m+1], q0.y, a1);
            a2 = fmaf(wode[4*m+2], q1.x, a2);
            a3 = fmaf(wode[4*m+3], q1.y, a3);
        }
        return reduce32((a0 + a1) + (a2 + a3));
    };
    auto h_axpy = [&](u32 p, float coef) {     // off critical path (after emit)
        const float* base = &k_lds[p & 1u][g * KS];
#pragma unroll
        for (int m = 0; m < 32; ++m) {
            float2 q = *(const float2*)(base + 2 * m);
            h[2*m+0] = fmaf(coef, q.x, h[2*m+0]);
            h[2*m+1] = fmaf(coef, q.y, h[2*m+1]);
        }
    };
    auto h_set = [&](u32 p) {
        const float* base = &k_lds[p & 1u][g * KS];
#pragma unroll
        for (int m = 0; m < 32; ++m) {
            float2 q = *(const float2*)(base + 2 * m);
            h[2*m+0] = q.x; h[2*m+1] = q.y;
        }
    };

    // ---- round 1: h0 = tanh(W_in x0 + b_in + b_hid) ----
    {
        const float* xr = x + g * 16;
        float a = 0.f;
#pragma unroll
        for (int q = 0; q < 4; ++q) {
            float4 v = *(const float4*)(xr + 4 * q);
            a = fmaf(win[4*q+0], v.x, a);
            a = fmaf(win[4*q+1], v.y, a);
            a = fmaf(win[4*q+2], v.z, a);
            a = fmaf(win[4*q+3], v.w, a);
        }
        emit(1, tanhf(reduce32(a) + bsum));
    }
    wait_all(1);
    float u_ = dot_chunk(1);
    float ub = u_ + breg;
    emit(2, tanhf(ub));            // k1 of (i=1, s=0)
    h_set(1);
    u32 p = 2;

    for (int i = 1; i < TSTEPS; ++i) {
        const float dt  = (t[i] - t[i - 1]) / (float)nstep;
        const float dt2 = 0.5f * dt;
        const float dt3 = dt * (1.0f / 3.0f);
        const float dt6 = dt * (1.0f / 6.0f);

        for (int s = 0; s < nstep; ++s) {
            const bool last = (s == nstep - 1);
            float w1, w2, w3;
            wait_all(p); w1 = dot_chunk(p);
            emit(p + 1, tanhf(ub + dt2 * w1)); h_axpy(p, dt6); ++p;
            wait_all(p); w2 = dot_chunk(p);
            emit(p + 1, tanhf(ub + dt2 * w2)); h_axpy(p, dt3); ++p;
            wait_all(p); w3 = dot_chunk(p);
            emit(p + 1, tanhf(ub + dt  * w3)); h_axpy(p, dt3); ++p;
            if (!last) {
                wait_all(p); float w4 = dot_chunk(p);
                u_ += dt6 * (w1 + 2.f * (w2 + w3) + w4);
                ub  = u_ + breg;
                emit(p + 1, tanhf(ub)); h_axpy(p, dt6); ++p;
            } else {
                // prefetch W_hid row + x_i while waiting
                const float* wr = W_hid + (size_t)row * HID + g * 64;
                float4 whv[16];
#pragma unroll
                for (int q = 0; q < 16; ++q) whv[q] = *(const float4*)(wr + 4 * q);
                const float* xr = x + (size_t)i * IN_DIM + g * 16;
                float4 xv[4];
#pragma unroll
                for (int q = 0; q < 4; ++q) xv[q] = *(const float4*)(xr + 4 * q);

                wait_all(p);
                h_axpy(p, dt6);               // fold k4 (needed before W_hid.h)
                float a0 = 0.f, a1 = 0.f, a2 = 0.f, a3 = 0.f;
#pragma unroll
                for (int q = 0; q < 16; ++q) {
                    a0 = fmaf(whv[q].x, h[4*q+0], a0);
                    a1 = fmaf(whv[q].y, h[4*q+1], a1);
                    a2 = fmaf(whv[q].z, h[4*q+2], a2);
                    a3 = fmaf(whv[q].w, h[4*q+3], a3);
                }
#pragma unroll
                for (int q = 0; q < 4; ++q) {
                    a0 = fmaf(win[4*q+0], xv[q].x, a0);
                    a1 = fmaf(win[4*q+1], xv[q].y, a1);
                    a2 = fmaf(win[4*q+2], xv[q].z, a2);
                    a3 = fmaf(win[4*q+3], xv[q].w, a3);
                }
                float r = reduce32((a0 + a1) + (a2 + a3));
                emit(p + 1, tanhf(r + bsum)); ++p;   // h_next broadcast
            }
        }
        if (i < TSTEPS - 1) {
            wait_all(p); u_ = dot_chunk(p); ub = u_ + breg;
            emit(p + 1, tanhf(ub)); h_set(p); ++p;   // k1 of next timestep
        } else {
            // final h broadcast at round p: only decode blocks consume
            if (bid < 64) {
                wait_all(p);
                const int r2 = bid * 8 + grp;
                const float* wd = W_dec + (size_t)r2 * HID + g * 64;
                const float* base = &k_lds[p & 1u][g * KS];
                float a0 = 0.f, a1 = 0.f, a2 = 0.f, a3 = 0.f;
#pragma unroll
                for (int m = 0; m < 16; ++m) {
                    float2 q0 = *(const float2*)(base + 4 * m);
                    float2 q1 = *(const float2*)(base + 4 * m + 2);
                    a0 = fmaf(wd[4*m+0], q0.x, a0);
                    a1 = fmaf(wd[4*m+1], q0.y, a1);
                    a2 = fmaf(wd[4*m+2], q1.x, a2);
                    a3 = fmaf(wd[4*m+3], q1.y, a3);
                }
                float r = reduce32((a0 + a1) + (a2 + a3));
                if (g == 0) out[r2] = r + b_dec[r2];
            }
            ++p;
        }
    }
}

extern "C" void kernel_launch(void* const* d_in, const int* in_sizes, int n_in,
                              void* d_out, int out_size, void* d_ws, size_t ws_size,
                              hipStream_t stream) {
    const float* x     = (const float*)d_in[0];
    const float* t     = (const float*)d_in[1];
    const float* W_in  = (const float*)d_in[2];
    const float* b_in  = (const float*)d_in[3];
    const float* W_hid = (const float*)d_in[4];
    const float* b_hid = (const float*)d_in[5];
    const float* W_ode = (const float*)d_in[6];
    const float* b_ode = (const float*)d_in[7];
    const float* W_dec = (const float*)d_in[8];
    const float* b_dec = (const float*)d_in[9];
    const int*   nstep = (const int*)d_in[10];
    ull* kb = (ull*)d_ws;                  // 2*2048*8B = 32 KB; 0xAA poison != any tag
    float* out = (float*)d_out;

    ode_rnn_main<<<dim3(NBLK), dim3(NTHR), 0, stream>>>(
        x, t, W_in, b_in, W_hid, b_hid, W_ode, b_ode, W_dec, b_dec,
        nstep, kb, out);
}

// Round 11
// 285345.239 us; speedup vs baseline: 2.2837x; 2.2524x over previous
//
#include <hip/hip_runtime.h>

#define HID 2048
#define IN_DIM 512
#define TSTEPS 1024
#define NBLK 256
#define NTHR 256
#define KS 66   // chunk stride (floats): 2-way bank alias = free, 8B aligned

typedef unsigned long long ull;
typedef unsigned int u32;
typedef __attribute__((ext_vector_type(4))) u32 u32x4;

__device__ __forceinline__ float reduce32(float v) {
    v += __shfl_xor(v, 16, 64);
    v += __shfl_xor(v, 8, 64);
    v += __shfl_xor(v, 4, 64);
    v += __shfl_xor(v, 2, 64);
    v += __shfl_xor(v, 1, 64);
    return v;
}

// 16B device-coherent (L2-bypassing) load/store: halves MALL request count
// vs 2x 8B agent atomics. Per-8B tag+payload halves cannot tear within one
// cache access; tag-verify retry remains the correctness guard.
__device__ __forceinline__ u32x4 load16_dev(const ull* p) {
    u32x4 r;
    asm volatile("global_load_dwordx4 %0, %1, off sc0 sc1\n\t"
                 "s_waitcnt vmcnt(0)"
                 : "=v"(r) : "v"(p) : "memory");
    return r;
}
__device__ __forceinline__ void store16_dev(ull* p, ull w0, ull w1) {
    u32x4 v;
    v.x = (u32)w0; v.y = (u32)(w0 >> 32);
    v.z = (u32)w1; v.w = (u32)(w1 >> 32);
    asm volatile("global_store_dwordx4 %0, %1, off sc0 sc1"
                 :: "v"(p), "v"(v) : "memory");
}

__global__ void __launch_bounds__(NTHR, 1)
ode_rnn_main(const float* __restrict__ x, const float* __restrict__ t,
             const float* __restrict__ W_in, const float* __restrict__ b_in,
             const float* __restrict__ W_hid, const float* __restrict__ b_hid,
             const float* __restrict__ W_ode, const float* __restrict__ b_ode,
             const float* __restrict__ W_dec, const float* __restrict__ b_dec,
             const int* __restrict__ nstep_p,
             ull* __restrict__ kb,          // kb[2][HID] tagged (round<<32|bits)
             float* __restrict__ out)
{
    __shared__ float k_lds[2][32 * KS];
    __shared__ u32 cnt[32];        // monotone per-chunk arrival counters
    __shared__ float gv[8];        // per-block row-leader gather
    __shared__ u32 gcnt;           // monotone emission arrivals
    __shared__ u32 clk;            // monotone clock flag

    const int tid = threadIdx.x;
    const int bid = blockIdx.x;
    const int g   = tid & 31;      // lane in 32-group == column-chunk index
    const int grp = tid >> 5;      // 0..7
    const int row = bid * 8 + grp;
    const int nstep = *nstep_p;
    const int clkline = (bid + 1) & (NBLK - 1);

    if (tid < 32) cnt[tid] = 0;
    if (tid == 0) { gcnt = 0; clk = 0; }

    // ---- per-lane weights ----
    float wode[64];
    {
        const float* wr = W_ode + (size_t)row * HID + g * 64;
#pragma unroll
        for (int q = 0; q < 16; ++q) {
            float4 v = *(const float4*)(wr + 4 * q);
            wode[4*q+0] = v.x; wode[4*q+1] = v.y;
            wode[4*q+2] = v.z; wode[4*q+3] = v.w;
        }
    }
    float win[16];
    {
        const float* wr = W_in + (size_t)row * IN_DIM + g * 16;
#pragma unroll
        for (int q = 0; q < 4; ++q) {
            float4 v = *(const float4*)(wr + 4 * q);
            win[4*q+0] = v.x; win[4*q+1] = v.y;
            win[4*q+2] = v.z; win[4*q+3] = v.w;
        }
    }
    const float breg = b_ode[row];
    const float bsum = b_in[row] + b_hid[row];

    float h[64];
    __syncthreads();               // cnt/gcnt/clk init visible

    // ---- emission: row-leaders gather in LDS; 8th arrival stores the line
    //      as 4x16B ascending (word 7 = gate word lands last) ----
    auto emit = [&](u32 p1, float y) {
        if (g == 0) {
            gv[grp] = y;
            u32 old = __hip_atomic_fetch_add(&gcnt, 1u, __ATOMIC_ACQ_REL,
                                             __HIP_MEMORY_SCOPE_WORKGROUP);
            if (old == 8u * p1 - 1u) {         // last of this emission
                ull* dst = kb + (size_t)(p1 & 1u) * HID + (size_t)bid * 8;
                const ull tag = ((ull)p1 << 32);
#pragma unroll
                for (int e = 0; e < 4; ++e) {
                    ull w0 = tag | (ull)__float_as_uint(gv[2*e+0]);
                    ull w1 = tag | (ull)__float_as_uint(gv[2*e+1]);
                    store16_dev(dst + 2*e, w0, w1);
                }
            }
        }
    };

    // ---- wait: clock = neighbor line's TAIL word (uniform, 1 req/iter) ->
    //      LDS flag -> one 4x16B sweep (tag-verified) -> per-chunk gate ----
    auto wait_all = [&](u32 p) {
        if (tid < 64) {
            ull* cw = kb + (size_t)(p & 1u) * HID + (size_t)clkline * 8 + 7;
            while ((u32)(__hip_atomic_load(cw, __ATOMIC_RELAXED,
                                           __HIP_MEMORY_SCOPE_AGENT) >> 32) != p) { }
            if (tid == 0)
                __hip_atomic_store(&clk, p, __ATOMIC_RELEASE,
                                   __HIP_MEMORY_SCOPE_WORKGROUP);
        }
        while (__hip_atomic_load(&clk, __ATOMIC_ACQUIRE,
                                 __HIP_MEMORY_SCOPE_WORKGROUP) < p) { }

        ull* src = kb + (size_t)(p & 1u) * HID + (size_t)tid * 8;
        u32x4 q0, q1, q2, q3;
        for (;;) {
            q0 = load16_dev(src + 0);
            q1 = load16_dev(src + 2);
            q2 = load16_dev(src + 4);
            q3 = load16_dev(src + 6);
            bool ok = (q0.y == p) & (q0.w == p) & (q1.y == p) & (q1.w == p)
                    & (q2.y == p) & (q2.w == p) & (q3.y == p) & (q3.w == p);
            if (ok) break;
            __builtin_amdgcn_s_sleep(1);      // straggler window only
        }
        float* dst = &k_lds[p & 1u][(tid >> 3) * KS + (tid & 7) * 8];
        dst[0] = __uint_as_float(q0.x); dst[1] = __uint_as_float(q0.z);
        dst[2] = __uint_as_float(q1.x); dst[3] = __uint_as_float(q1.z);
        dst[4] = __uint_as_float(q2.x); dst[5] = __uint_as_float(q2.z);
        dst[6] = __uint_as_float(q3.x); dst[7] = __uint_as_float(q3.z);
        __hip_atomic_fetch_add(&cnt[tid >> 3], 1u, __ATOMIC_RELEASE,
                               __HIP_MEMORY_SCOPE_WORKGROUP);
        const u32 need = 8u * p;
        while (__hip_atomic_load(&cnt[g], __ATOMIC_ACQUIRE,
                                 __HIP_MEMORY_SCOPE_WORKGROUP) < need) { }
    };

    auto dot_chunk = [&](u32 p) -> float {
        const float* base = &k_lds[p & 1u][g * KS];
        float a0 = 0.f, a1 = 0.f, a2 = 0.f, a3 = 0.f;
#pragma unroll
        for (int m = 0; m < 16; ++m) {
            float2 q0 = *(const float2*)(base + 4 * m);
            float2 q1 = *(const float2*)(base + 4 * m + 2);
            a0 = fmaf(wode[4*m+0], q0.x, a0);
            a1 = fmaf(wode[4*m+1], q0.y, a1);
            a2 = fmaf(wode[4*m+2], q1.x, a2);
            a3 = fmaf(wode[4*m+3], q1.y, a3);
        }
        return reduce32((a0 + a1) + (a2 + a3));
    };
    auto h_axpy = [&](u32 p, float coef) {     // off critical path (after emit)
        const float* base = &k_lds[p & 1u][g * KS];
#pragma unroll
        for (int m = 0; m < 32; ++m) {
            float2 q = *(const float2*)(base + 2 * m);
            h[2*m+0] = fmaf(coef, q.x, h[2*m+0]);
            h[2*m+1] = fmaf(coef, q.y, h[2*m+1]);
        }
    };
    auto h_set = [&](u32 p) {
        const float* base = &k_lds[p & 1u][g * KS];
#pragma unroll
        for (int m = 0; m < 32; ++m) {
            float2 q = *(const float2*)(base + 2 * m);
            h[2*m+0] = q.x; h[2*m+1] = q.y;
        }
    };

    // ---- round 1: h0 = tanh(W_in x0 + b_in + b_hid) ----
    {
        const float* xr = x + g * 16;
        float a = 0.f;
#pragma unroll
        for (int q = 0; q < 4; ++q) {
            float4 v = *(const float4*)(xr + 4 * q);
            a = fmaf(win[4*q+0], v.x, a);
            a = fmaf(win[4*q+1], v.y, a);
            a = fmaf(win[4*q+2], v.z, a);
            a = fmaf(win[4*q+3], v.w, a);
        }
        emit(1, tanhf(reduce32(a) + bsum));
    }
    wait_all(1);
    float u_ = dot_chunk(1);
    float ub = u_ + breg;
    emit(2, tanhf(ub));            // k1 of (i=1, s=0)
    h_set(1);
    u32 p = 2;

    for (int i = 1; i < TSTEPS; ++i) {
        const float dt  = (t[i] - t[i - 1]) / (float)nstep;
        const float dt2 = 0.5f * dt;
        const float dt3 = dt * (1.0f / 3.0f);
        const float dt6 = dt * (1.0f / 6.0f);

        for (int s = 0; s < nstep; ++s) {
            const bool last = (s == nstep - 1);
            float w1, w2, w3;
            wait_all(p); w1 = dot_chunk(p);
            emit(p + 1, tanhf(ub + dt2 * w1)); h_axpy(p, dt6); ++p;
            wait_all(p); w2 = dot_chunk(p);
            emit(p + 1, tanhf(ub + dt2 * w2)); h_axpy(p, dt3); ++p;
            wait_all(p); w3 = dot_chunk(p);
            emit(p + 1, tanhf(ub + dt  * w3)); h_axpy(p, dt3); ++p;
            if (!last) {
                wait_all(p); float w4 = dot_chunk(p);
                u_ += dt6 * (w1 + 2.f * (w2 + w3) + w4);
                ub  = u_ + breg;
                emit(p + 1, tanhf(ub)); h_axpy(p, dt6); ++p;
            } else {
                // prefetch W_hid row + x_i while waiting
                const float* wr = W_hid + (size_t)row * HID + g * 64;
                float4 whv[16];
#pragma unroll
                for (int q = 0; q < 16; ++q) whv[q] = *(const float4*)(wr + 4 * q);
                const float* xr = x + (size_t)i * IN_DIM + g * 16;
                float4 xv[4];
#pragma unroll
                for (int q = 0; q < 4; ++q) xv[q] = *(const float4*)(xr + 4 * q);

                wait_all(p);
                h_axpy(p, dt6);               // fold k4 (needed before W_hid.h)
                float a0 = 0.f, a1 = 0.f, a2 = 0.f, a3 = 0.f;
#pragma unroll
                for (int q = 0; q < 16; ++q) {
                    a0 = fmaf(whv[q].x, h[4*q+0], a0);
                    a1 = fmaf(whv[q].y, h[4*q+1], a1);
                    a2 = fmaf(whv[q].z, h[4*q+2], a2);
                    a3 = fmaf(whv[q].w, h[4*q+3], a3);
                }
#pragma unroll
                for (int q = 0; q < 4; ++q) {
                    a0 = fmaf(win[4*q+0], xv[q].x, a0);
                    a1 = fmaf(win[4*q+1], xv[q].y, a1);
                    a2 = fmaf(win[4*q+2], xv[q].z, a2);
                    a3 = fmaf(win[4*q+3], xv[q].w, a3);
                }
                float r = reduce32((a0 + a1) + (a2 + a3));
                emit(p + 1, tanhf(r + bsum)); ++p;   // h_next broadcast
            }
        }
        if (i < TSTEPS - 1) {
            wait_all(p); u_ = dot_chunk(p); ub = u_ + breg;
            emit(p + 1, tanhf(ub)); h_set(p); ++p;   // k1 of next timestep
        } else {
            // final h broadcast at round p: only decode blocks consume
            if (bid < 64) {
                wait_all(p);
                const int r2 = bid * 8 + grp;
                const float* wd = W_dec + (size_t)r2 * HID + g * 64;
                const float* base = &k_lds[p & 1u][g * KS];
                float a0 = 0.f, a1 = 0.f, a2 = 0.f, a3 = 0.f;
#pragma unroll
                for (int m = 0; m < 16; ++m) {
                    float2 q0 = *(const float2*)(base + 4 * m);
                    float2 q1 = *(const float2*)(base + 4 * m + 2);
                    a0 = fmaf(wd[4*m+0], q0.x, a0);
                    a1 = fmaf(wd[4*m+1], q0.y, a1);
                    a2 = fmaf(wd[4*m+2], q1.x, a2);
                    a3 = fmaf(wd[4*m+3], q1.y, a3);
                }
                float r = reduce32((a0 + a1) + (a2 + a3));
                if (g == 0) out[r2] = r + b_dec[r2];
            }
            ++p;
        }
    }
}

extern "C" void kernel_launch(void* const* d_in, const int* in_sizes, int n_in,
                              void* d_out, int out_size, void* d_ws, size_t ws_size,
                              hipStream_t stream) {
    const float* x     = (const float*)d_in[0];
    const float* t     = (const float*)d_in[1];
    const float* W_in  = (const float*)d_in[2];
    const float* b_in  = (const float*)d_in[3];
    const float* W_hid = (const float*)d_in[4];
    const float* b_hid = (const float*)d_in[5];
    const float* W_ode = (const float*)d_in[6];
    const float* b_ode = (const float*)d_in[7];
    const float* W_dec = (const float*)d_in[8];
    const float* b_dec = (const float*)d_in[9];
    const int*   nstep = (const int*)d_in[10];
    ull* kb = (ull*)d_ws;                  // 2*2048*8B = 32 KB; 0xAA poison != any tag
    float* out = (float*)d_out;

    ode_rnn_main<<<dim3(NBLK), dim3(NTHR), 0, stream>>>(
        x, t, W_in, b_in, W_hid, b_hid, W_ode, b_ode, W_dec, b_dec,
        nstep, kb, out);
}

// Round 12
// 246589.307 us; speedup vs baseline: 2.6426x; 1.1572x over previous
//
#include <hip/hip_runtime.h>

#define HID 2048
#define IN_DIM 512
#define TSTEPS 1024
#define NBLK 256
#define NTHR 256
#define KS 66   // chunk stride (floats): 2-way bank alias = free, 8B aligned

typedef unsigned long long ull;
typedef unsigned int u32;
typedef __attribute__((ext_vector_type(4))) u32 u32x4;

__device__ __forceinline__ float reduce32(float v) {
    v += __shfl_xor(v, 16, 64);
    v += __shfl_xor(v, 8, 64);
    v += __shfl_xor(v, 4, 64);
    v += __shfl_xor(v, 2, 64);
    v += __shfl_xor(v, 1, 64);
    return v;
}

// 16B device-coherent (L2-bypassing) accesses: coalescing + minimal MALL
// request count. Sweep: issue ALL FOUR loads, then ONE vmcnt(0) -> 1 RT
// instead of 4 serialized RTs (r11's per-load waitcnt bug).
__device__ __forceinline__ void sweep_load16x4(const ull* p,
                                               u32x4& a, u32x4& b,
                                               u32x4& c, u32x4& d) {
    asm volatile(
        "global_load_dwordx4 %0, %4, off sc0 sc1\n\t"
        "global_load_dwordx4 %1, %5, off sc0 sc1\n\t"
        "global_load_dwordx4 %2, %6, off sc0 sc1\n\t"
        "global_load_dwordx4 %3, %7, off sc0 sc1\n\t"
        "s_waitcnt vmcnt(0)"
        : "=&v"(a), "=&v"(b), "=&v"(c), "=&v"(d)
        : "v"(p), "v"(p + 2), "v"(p + 4), "v"(p + 6)
        : "memory");
}
__device__ __forceinline__ void store16_dev(ull* p, ull w0, ull w1) {
    u32x4 v;
    v.x = (u32)w0; v.y = (u32)(w0 >> 32);
    v.z = (u32)w1; v.w = (u32)(w1 >> 32);
    asm volatile("global_store_dwordx4 %0, %1, off sc0 sc1"
                 :: "v"(p), "v"(v) : "memory");
}

__global__ void __launch_bounds__(NTHR, 1)
ode_rnn_main(const float* __restrict__ x, const float* __restrict__ t,
             const float* __restrict__ W_in, const float* __restrict__ b_in,
             const float* __restrict__ W_hid, const float* __restrict__ b_hid,
             const float* __restrict__ W_ode, const float* __restrict__ b_ode,
             const float* __restrict__ W_dec, const float* __restrict__ b_dec,
             const int* __restrict__ nstep_p,
             ull* __restrict__ kb,          // kb[2][HID] tagged (round<<32|bits)
             float* __restrict__ out)
{
    __shared__ float k_lds[2][32 * KS];
    __shared__ u32 cnt[32];        // monotone per-chunk arrival counters
    __shared__ float gv[8];        // per-block row-leader gather
    __shared__ u32 gcnt;           // monotone emission arrivals
    __shared__ u32 clk;            // monotone clock flag

    const int tid = threadIdx.x;
    const int bid = blockIdx.x;
    const int g   = tid & 31;      // lane in 32-group == column-chunk index
    const int grp = tid >> 5;      // 0..7
    const int row = bid * 8 + grp;
    const int nstep = *nstep_p;
    const int clkline = (bid + 1) & (NBLK - 1);

    if (tid < 32) cnt[tid] = 0;
    if (tid == 0) { gcnt = 0; clk = 0; }

    // ---- per-lane weights ----
    float wode[64];
    {
        const float* wr = W_ode + (size_t)row * HID + g * 64;
#pragma unroll
        for (int q = 0; q < 16; ++q) {
            float4 v = *(const float4*)(wr + 4 * q);
            wode[4*q+0] = v.x; wode[4*q+1] = v.y;
            wode[4*q+2] = v.z; wode[4*q+3] = v.w;
        }
    }
    float win[16];
    {
        const float* wr = W_in + (size_t)row * IN_DIM + g * 16;
#pragma unroll
        for (int q = 0; q < 4; ++q) {
            float4 v = *(const float4*)(wr + 4 * q);
            win[4*q+0] = v.x; win[4*q+1] = v.y;
            win[4*q+2] = v.z; win[4*q+3] = v.w;
        }
    }
    const float breg = b_ode[row];
    const float bsum = b_in[row] + b_hid[row];

    float h[64];
    __syncthreads();               // cnt/gcnt/clk init visible

    // ---- emission: row-leaders gather in LDS; 8th arrival stores the line
    //      as 4x16B ascending (word 7 = gate word issued last) ----
    auto emit = [&](u32 p1, float y) {
        if (g == 0) {
            gv[grp] = y;
            u32 old = __hip_atomic_fetch_add(&gcnt, 1u, __ATOMIC_ACQ_REL,
                                             __HIP_MEMORY_SCOPE_WORKGROUP);
            if (old == 8u * p1 - 1u) {         // last of this emission
                ull* dst = kb + (size_t)(p1 & 1u) * HID + (size_t)bid * 8;
                const ull tag = ((ull)p1 << 32);
#pragma unroll
                for (int e = 0; e < 4; ++e) {
                    ull w0 = tag | (ull)__float_as_uint(gv[2*e+0]);
                    ull w1 = tag | (ull)__float_as_uint(gv[2*e+1]);
                    store16_dev(dst + 2*e, w0, w1);
                }
            }
        }
    };

    // ---- wait: clock = neighbor line's TAIL word (uniform, 1 req/iter) ->
    //      LDS flag -> one batched 4x16B sweep (tag-verified) -> chunk gate ----
    auto wait_all = [&](u32 p) {
        if (tid < 64) {
            ull* cw = kb + (size_t)(p & 1u) * HID + (size_t)clkline * 8 + 7;
            while ((u32)(__hip_atomic_load(cw, __ATOMIC_RELAXED,
                                           __HIP_MEMORY_SCOPE_AGENT) >> 32) != p) { }
            if (tid == 0)
                __hip_atomic_store(&clk, p, __ATOMIC_RELEASE,
                                   __HIP_MEMORY_SCOPE_WORKGROUP);
        }
        while (__hip_atomic_load(&clk, __ATOMIC_ACQUIRE,
                                 __HIP_MEMORY_SCOPE_WORKGROUP) < p) { }

        ull* src = kb + (size_t)(p & 1u) * HID + (size_t)tid * 8;
        u32x4 q0, q1, q2, q3;
        for (;;) {
            sweep_load16x4(src, q0, q1, q2, q3);   // 4 issues, ONE wait: 1 RT
            bool ok = (q0.y == p) & (q0.w == p) & (q1.y == p) & (q1.w == p)
                    & (q2.y == p) & (q2.w == p) & (q3.y == p) & (q3.w == p);
            if (ok) break;
            __builtin_amdgcn_s_sleep(1);      // straggler window only
        }
        float* dst = &k_lds[p & 1u][(tid >> 3) * KS + (tid & 7) * 8];
        dst[0] = __uint_as_float(q0.x); dst[1] = __uint_as_float(q0.z);
        dst[2] = __uint_as_float(q1.x); dst[3] = __uint_as_float(q1.z);
        dst[4] = __uint_as_float(q2.x); dst[5] = __uint_as_float(q2.z);
        dst[6] = __uint_as_float(q3.x); dst[7] = __uint_as_float(q3.z);
        __hip_atomic_fetch_add(&cnt[tid >> 3], 1u, __ATOMIC_RELEASE,
                               __HIP_MEMORY_SCOPE_WORKGROUP);
        const u32 need = 8u * p;
        while (__hip_atomic_load(&cnt[g], __ATOMIC_ACQUIRE,
                                 __HIP_MEMORY_SCOPE_WORKGROUP) < need) { }
    };

    auto dot_chunk = [&](u32 p) -> float {
        const float* base = &k_lds[p & 1u][g * KS];
        float a0 = 0.f, a1 = 0.f, a2 = 0.f, a3 = 0.f;
#pragma unroll
        for (int m = 0; m < 16; ++m) {
            float2 q0 = *(const float2*)(base + 4 * m);
            float2 q1 = *(const float2*)(base + 4 * m + 2);
            a0 = fmaf(wode[4*m+0], q0.x, a0);
            a1 = fmaf(wode[4*m+1], q0.y, a1);
            a2 = fmaf(wode[4*m+2], q1.x, a2);
            a3 = fmaf(wode[4*m+3], q1.y, a3);
        }
        return reduce32((a0 + a1) + (a2 + a3));
    };
    auto h_axpy = [&](u32 p, float coef) {     // off critical path (after emit)
        const float* base = &k_lds[p & 1u][g * KS];
#pragma unroll
        for (int m = 0; m < 32; ++m) {
            float2 q = *(const float2*)(base + 2 * m);
            h[2*m+0] = fmaf(coef, q.x, h[2*m+0]);
            h[2*m+1] = fmaf(coef, q.y, h[2*m+1]);
        }
    };
    auto h_set = [&](u32 p) {
        const float* base = &k_lds[p & 1u][g * KS];
#pragma unroll
        for (int m = 0; m < 32; ++m) {
            float2 q = *(const float2*)(base + 2 * m);
            h[2*m+0] = q.x; h[2*m+1] = q.y;
        }
    };

    // ---- round 1: h0 = tanh(W_in x0 + b_in + b_hid) ----
    {
        const float* xr = x + g * 16;
        float a = 0.f;
#pragma unroll
        for (int q = 0; q < 4; ++q) {
            float4 v = *(const float4*)(xr + 4 * q);
            a = fmaf(win[4*q+0], v.x, a);
            a = fmaf(win[4*q+1], v.y, a);
            a = fmaf(win[4*q+2], v.z, a);
            a = fmaf(win[4*q+3], v.w, a);
        }
        emit(1, tanhf(reduce32(a) + bsum));
    }
    wait_all(1);
    float u_ = dot_chunk(1);
    float ub = u_ + breg;
    emit(2, tanhf(ub));            // k1 of (i=1, s=0)
    h_set(1);
    u32 p = 2;

    for (int i = 1; i < TSTEPS; ++i) {
        const float dt  = (t[i] - t[i - 1]) / (float)nstep;
        const float dt2 = 0.5f * dt;
        const float dt3 = dt * (1.0f / 3.0f);
        const float dt6 = dt * (1.0f / 6.0f);

        for (int s = 0; s < nstep; ++s) {
            const bool last = (s == nstep - 1);
            float w1, w2, w3;
            wait_all(p); w1 = dot_chunk(p);
            emit(p + 1, tanhf(ub + dt2 * w1)); h_axpy(p, dt6); ++p;
            wait_all(p); w2 = dot_chunk(p);
            emit(p + 1, tanhf(ub + dt2 * w2)); h_axpy(p, dt3); ++p;
            wait_all(p); w3 = dot_chunk(p);
            emit(p + 1, tanhf(ub + dt  * w3)); h_axpy(p, dt3); ++p;
            if (!last) {
                wait_all(p); float w4 = dot_chunk(p);
                u_ += dt6 * (w1 + 2.f * (w2 + w3) + w4);
                ub  = u_ + breg;
                emit(p + 1, tanhf(ub)); h_axpy(p, dt6); ++p;
            } else {
                // prefetch W_hid row + x_i while waiting
                const float* wr = W_hid + (size_t)row * HID + g * 64;
                float4 whv[16];
#pragma unroll
                for (int q = 0; q < 16; ++q) whv[q] = *(const float4*)(wr + 4 * q);
                const float* xr = x + (size_t)i * IN_DIM + g * 16;
                float4 xv[4];
#pragma unroll
                for (int q = 0; q < 4; ++q) xv[q] = *(const float4*)(xr + 4 * q);

                wait_all(p);
                h_axpy(p, dt6);               // fold k4 (needed before W_hid.h)
                float a0 = 0.f, a1 = 0.f, a2 = 0.f, a3 = 0.f;
#pragma unroll
                for (int q = 0; q < 16; ++q) {
                    a0 = fmaf(whv[q].x, h[4*q+0], a0);
                    a1 = fmaf(whv[q].y, h[4*q+1], a1);
                    a2 = fmaf(whv[q].z, h[4*q+2], a2);
                    a3 = fmaf(whv[q].w, h[4*q+3], a3);
                }
#pragma unroll
                for (int q = 0; q < 4; ++q) {
                    a0 = fmaf(win[4*q+0], xv[q].x, a0);
                    a1 = fmaf(win[4*q+1], xv[q].y, a1);
                    a2 = fmaf(win[4*q+2], xv[q].z, a2);
                    a3 = fmaf(win[4*q+3], xv[q].w, a3);
                }
                float r = reduce32((a0 + a1) + (a2 + a3));
                emit(p + 1, tanhf(r + bsum)); ++p;   // h_next broadcast
            }
        }
        if (i < TSTEPS - 1) {
            wait_all(p); u_ = dot_chunk(p); ub = u_ + breg;
            emit(p + 1, tanhf(ub)); h_set(p); ++p;   // k1 of next timestep
        } else {
            // final h broadcast at round p: only decode blocks consume
            if (bid < 64) {
                wait_all(p);
                const int r2 = bid * 8 + grp;
                const float* wd = W_dec + (size_t)r2 * HID + g * 64;
                const float* base = &k_lds[p & 1u][g * KS];
                float a0 = 0.f, a1 = 0.f, a2 = 0.f, a3 = 0.f;
#pragma unroll
                for (int m = 0; m < 16; ++m) {
                    float2 q0 = *(const float2*)(base + 4 * m);
                    float2 q1 = *(const float2*)(base + 4 * m + 2);
                    a0 = fmaf(wd[4*m+0], q0.x, a0);
                    a1 = fmaf(wd[4*m+1], q0.y, a1);
                    a2 = fmaf(wd[4*m+2], q1.x, a2);
                    a3 = fmaf(wd[4*m+3], q1.y, a3);
                }
                float r = reduce32((a0 + a1) + (a2 + a3));
                if (g == 0) out[r2] = r + b_dec[r2];
            }
            ++p;
        }
    }
}

extern "C" void kernel_launch(void* const* d_in, const int* in_sizes, int n_in,
                              void* d_out, int out_size, void* d_ws, size_t ws_size,
                              hipStream_t stream) {
    const float* x     = (const float*)d_in[0];
    const float* t     = (const float*)d_in[1];
    const float* W_in  = (const float*)d_in[2];
    const float* b_in  = (const float*)d_in[3];
    const float* W_hid = (const float*)d_in[4];
    const float* b_hid = (const float*)d_in[5];
    const float* W_ode = (const float*)d_in[6];
    const float* b_ode = (const float*)d_in[7];
    const float* W_dec = (const float*)d_in[8];
    const float* b_dec = (const float*)d_in[9];
    const int*   nstep = (const int*)d_in[10];
    ull* kb = (ull*)d_ws;                  // 2*2048*8B = 32 KB; 0xAA poison != any tag
    float* out = (float*)d_out;

    ode_rnn_main<<<dim3(NBLK), dim3(NTHR), 0, stream>>>(
        x, t, W_in, b_in, W_hid, b_hid, W_ode, b_ode, W_dec, b_dec,
        nstep, kb, out);
}